// Round 12
// baseline (215.172 us; speedup 1.0000x reference)
//
#include <hip/hip_runtime.h>
#include <math.h>

#define NN 50000
#define NE 800000
#define DIM 128
#define NGR 128
#define MP_SLICES 16

// edge partition params
#define PCHUNK 2048
#define PNBLK 391      // ceil(NE/PCHUNK)
#define NBIN 196       // bin = dst>>8 ; 256 nodes per bin

// bn stats blocks
#define BN_NB 1024

// K1 fat-kernel block ranges: [0,32)=pack, [32,423)=hist, [423,1447)=bn_stats
#define K1_PACK_NB   32
#define K1_HIST_END  (K1_PACK_NB + PNBLK)          // 423
#define K1_TOTAL     (K1_HIST_END + BN_NB)         // 1447
// K2: [0,196)=scan_cols, 196=bn_final, [197,295)=graph_bounds (512 thr)
#define K2_GB_NB     98
#define K2_TOTAL     (NBIN + 1 + K2_GB_NB)         // 295
// K4: [0,196)=csr_build, [196,196+6250)=bn_apply
#define K4_BNA_NB    6250
#define K4_TOTAL     (NBIN + K4_BNA_NB)            // 6446

typedef short bf16x8 __attribute__((ext_vector_type(8)));
typedef float f32x4  __attribute__((ext_vector_type(4)));

// ---- workspace layout (bytes) ----
#define OFF_FLAG    0
#define OFF_SCALE   1024
#define OFF_SHIFT   2048
#define OFF_GSTART  4096                   // 129 ints
#define OFF_TOT     16384                  // NBIN ints
#define OFF_WC1     32768                  // frag-major weights, 64KB
#define OFF_WC2     98304                  // 64KB, ends 163840
#define OFF_PSUM    262144                 // BN_NB*128*4 = 512KB, ends 786432
#define OFF_PSQ     786432                 // 512KB, ends 1310720
#define OFF_RSTART  1310720                // (NN+1) ints, ends 1510724
#define OFF_CSR     1572864                // 3.2MB, ends 4772864
#define OFF_PART    4772864                // 1MB maxpool partials, ends 5821440
#define OFF_HIST    5821440                // PNBLK*NBIN ints = 306544, ends 6127984
#define OFF_OFFG    6127984                // 306544, ends 6434528
#define OFF_BEDGE   6553600                // 3.2MB packed u32 (dst8|src16), ends 9753600
#define OFF_H0B     13000000               // 12.8MB bf16
#define OFF_H1B     26000000               // 12.8MB bf16
#define OFF_AGGB    39000000               // 12.8MB bf16
#define WS_NEED     52000000

__device__ __forceinline__ unsigned short f2b(float f) {
  union { float f; unsigned u; } v; v.f = f;
  unsigned r = (v.u + 0x7FFF + ((v.u >> 16) & 1)) >> 16;   // RNE
  return (unsigned short)r;
}
__device__ __forceinline__ float b2f(unsigned short h) {
  union { unsigned u; float f; } v; v.u = ((unsigned)h) << 16;
  return v.f;
}

// ---- K1: pack_weights || part_hist || bn_stats (all independent) ----
// hist blocks self-probe index width (no intra-kernel dep on flag).
__global__ __launch_bounds__(256) void k1_prep(
    const float* __restrict__ W1l, const float* __restrict__ W1r,
    const float* __restrict__ W2l, const float* __restrict__ W2r,
    unsigned short* __restrict__ Wf1, unsigned short* __restrict__ Wf2,
    const void* __restrict__ edge, int* __restrict__ flag,
    int* __restrict__ hist,
    const float* __restrict__ x, float* __restrict__ psum, float* __restrict__ psq) {
  int b = blockIdx.x, t = threadIdx.x;

  if (b < K1_PACK_NB) {
    // pack both layers' weights into fragment-major bf16 (8192 threads)
    int gi = b*256 + t;
    if (gi == 0) {
      const unsigned* eu = (const unsigned*)edge;
      unsigned acc = 0;
      for (int i = 0; i < 64; ++i) acc |= eu[2*i+1];
      *flag = (acc == 0) ? 1 : 0;
    }
    int layer = gi >> 12;        // 0 or 1
    int i = gi & 4095;           // frag*64 + lane, i < 4096
    const float* Wl = layer ? W2l : W1l;
    const float* Wr = layer ? W2r : W1r;
    unsigned short* Wfrag = layer ? Wf2 : Wf1;
    int lane = i & 63, f = i >> 6;
    int kc = f >> 3, jf = f & 7;
    int j  = jf*16 + (lane & 15);
    int k0 = kc*32 + 8*(lane >> 4);
    #pragma unroll
    for (int e = 0; e < 8; ++e) {
      int k = k0 + e;
      float v = (k < 128) ? Wl[j*128 + k] : Wr[j*128 + (k-128)];
      Wfrag[(size_t)i*8 + e] = f2b(v);
    }
    return;
  }

  if (b < K1_HIST_END) {
    // part_hist chunk
    __shared__ int lh[NBIN];
    __shared__ int wflag;
    int bb = b - K1_PACK_NB;
    if (t < NBIN) lh[t] = 0;
    if (t == 0) {   // self-probe width (512B, L2-hot)
      const unsigned* eu = (const unsigned*)edge;
      unsigned acc = 0;
      for (int i = 0; i < 64; ++i) acc |= eu[2*i+1];
      wflag = (acc == 0) ? 1 : 0;
    }
    __syncthreads();
    bool w = (wflag != 0);
    int e0 = bb*PCHUNK, e1 = e0 + PCHUNK; if (e1 > NE) e1 = NE;
    for (int e = e0 + t; e < e1; e += 256) {
      int d = w ? (int)((const long long*)edge)[NE + e] : ((const int*)edge)[NE + e];
      atomicAdd(&lh[d >> 8], 1);
    }
    __syncthreads();
    if (t < NBIN) hist[bb*NBIN + t] = lh[t];
    return;
  }

  {
    // bn_stats block
    __shared__ float ss[128], sq[128];
    int bb = b - K1_HIST_END;
    int col  = t & 127;
    int half = t >> 7;
    float s = 0.f, q = 0.f;
    for (int r = bb*2 + half; r < NN; r += 2*BN_NB) {
      float v = x[(size_t)r*DIM + col];
      s += v; q += v*v;
    }
    if (half) { ss[col] = s; sq[col] = q; }
    __syncthreads();
    if (!half) {
      psum[bb*DIM + col] = s + ss[col];
      psq [bb*DIM + col] = q + sq[col];
    }
    return;
  }
}

// ---- K2: part_scan_cols || bn_final || graph_bounds (512 threads) ----
__global__ __launch_bounds__(512) void k2_scan(
    const int* __restrict__ hist, int* __restrict__ offg, int* __restrict__ tot,
    const float* __restrict__ psum, const float* __restrict__ psq,
    const float* __restrict__ gamma, const float* __restrict__ beta,
    float* __restrict__ sc, float* __restrict__ sh,
    const void* __restrict__ batch, const int* __restrict__ flag,
    int* __restrict__ gstart) {
  int b = blockIdx.x, t = threadIdx.x;

  if (b < NBIN) {
    // exclusive scan over this bin's PNBLK chunk counts
    __shared__ int sm[512];
    int bin = b;
    int v = (t < PNBLK) ? hist[t*NBIN + bin] : 0;
    sm[t] = v;
    __syncthreads();
    for (int off = 1; off < 512; off <<= 1) {
      int xx = (t >= off) ? sm[t-off] : 0;
      __syncthreads();
      sm[t] += xx;
      __syncthreads();
    }
    if (t < PNBLK) offg[t*NBIN + bin] = sm[t] - v;
    if (t == 511) tot[bin] = sm[511];
    return;
  }

  if (b == NBIN) {
    // bn_final: 4 groups of 128 cols
    __shared__ float ss[4][128], qq[4][128];
    int col = t & 127, g = t >> 7;
    float s = 0.f, q = 0.f;
    for (int i = g; i < BN_NB; i += 4) {
      s += psum[i*DIM + col];
      q += psq [i*DIM + col];
    }
    ss[g][col] = s; qq[g][col] = q;
    __syncthreads();
    if (g == 0) {
      #pragma unroll
      for (int k = 1; k < 4; ++k) { s += ss[k][col]; q += qq[k][col]; }
      float mu  = s * (1.0f/NN);
      float var = q * (1.0f/NN) - mu*mu;     // biased variance
      float a = gamma[col] * rsqrtf(var + 1e-5f);
      sc[col] = a;
      sh[col] = beta[col] - mu*a;
    }
    return;
  }

  {
    // graph_bounds: gstart[g] = lower_bound(batch, g)
    int n = (b - NBIN - 1)*512 + t;
    if (n > NN) return;
    bool w = (*flag != 0);
    int bn = NGR, bp = -1;
    if (n < NN) bn = w ? (int)((const long long*)batch)[n]   : ((const int*)batch)[n];
    if (n > 0)  bp = w ? (int)((const long long*)batch)[n-1] : ((const int*)batch)[n-1];
    for (int g = bp + 1; g <= bn; ++g) gstart[g] = n;
    return;
  }
}

// ---- K3: partition pass (unchanged logic) ----
__global__ __launch_bounds__(256) void part_scatter(const void* __restrict__ edge,
                                                    const int* __restrict__ flag,
                                                    const int* __restrict__ offg,
                                                    const int* __restrict__ tot,
                                                    unsigned* __restrict__ bpack) {
  __shared__ int sm[256];
  __shared__ int cur[NBIN];
  int b = blockIdx.x, t = threadIdx.x;
  int v = (t < NBIN) ? tot[t] : 0;
  sm[t] = v;
  __syncthreads();
  for (int off = 1; off < 256; off <<= 1) {
    int xx = (t >= off) ? sm[t-off] : 0;
    __syncthreads();
    sm[t] += xx;
    __syncthreads();
  }
  if (t < NBIN) cur[t] = offg[b*NBIN + t] + sm[t] - v;   // + bstart[t]
  __syncthreads();
  bool w = (*flag != 0);
  int e0 = b*PCHUNK, e1 = e0 + PCHUNK; if (e1 > NE) e1 = NE;
  for (int e = e0 + t; e < e1; e += 256) {
    int s, d;
    if (w) {
      s = (int)((const long long*)edge)[e];
      d = (int)((const long long*)edge)[NE + e];
    } else {
      s = ((const int*)edge)[e];
      d = ((const int*)edge)[NE + e];
    }
    int pos = atomicAdd(&cur[d >> 8], 1);   // LDS atomic only
    bpack[pos] = ((unsigned)(d & 255) << 16) | (unsigned)s;   // src < 2^16
  }
}

// ---- K4: csr_build || bn_apply ----
__global__ __launch_bounds__(256) void k4_csr_bn(
    const unsigned* __restrict__ bpack, const int* __restrict__ tot,
    int* __restrict__ row_start, int* __restrict__ csr_src,
    const float* __restrict__ x, const float* __restrict__ sc,
    const float* __restrict__ sh, unsigned short* __restrict__ h0) {
  int b = blockIdx.x, t = threadIdx.x;

  if (b < NBIN) {
    __shared__ int sm[256];
    __shared__ int ldeg[256];
    __shared__ int lscan[256];
    __shared__ int lcur[256];
    __shared__ int e0s, e1s;
    int i = b;
    int v = (t < NBIN) ? tot[t] : 0;
    sm[t] = v;
    __syncthreads();
    for (int off = 1; off < 256; off <<= 1) {
      int xx = (t >= off) ? sm[t-off] : 0;
      __syncthreads();
      sm[t] += xx;
      __syncthreads();
    }
    if (t == i) { e0s = sm[t] - v; e1s = sm[t]; }
    ldeg[t] = 0;
    __syncthreads();
    int e0 = e0s, e1 = e1s;
    for (int p = e0 + t; p < e1; p += 256) {
      unsigned pv = bpack[p];
      atomicAdd(&ldeg[(pv >> 16) & 255], 1);
    }
    __syncthreads();
    if (t == 0) {
      int run = 0;
      for (int k = 0; k < 256; ++k) { lscan[k] = run; run += ldeg[k]; }
    }
    __syncthreads();
    int node = i*256 + t;
    if (node <= NN) row_start[node] = e0 + lscan[t];
    lcur[t] = lscan[t];
    __syncthreads();
    for (int p = e0 + t; p < e1; p += 256) {
      unsigned pv = bpack[p];
      int d8 = (pv >> 16) & 255;
      int s  = (int)(pv & 0xffffu);
      int pos = atomicAdd(&lcur[d8], 1);
      csr_src[e0 + pos] = s;
    }
    return;
  }

  {
    // bn_apply: x fp32 -> h0 bf16
    long i = (long)(b - NBIN)*256 + t;
    if (i >= (long)NN*DIM/4) return;
    int c4 = (int)((i*4) & (DIM-1));
    float4 v = ((const float4*)x)[i];
    ushort4 r;
    r.x = f2b(v.x*sc[c4+0] + sh[c4+0]);
    r.y = f2b(v.y*sc[c4+1] + sh[c4+1]);
    r.z = f2b(v.z*sc[c4+2] + sh[c4+2]);
    r.w = f2b(v.w*sc[c4+3] + sh[c4+3]);
    ((ushort4*)h0)[i] = r;
    return;
  }
}

// one wave per node; 4 lane-groups of 16, each group runs FOUR independent
// neighbor streams (p0+grp*4+{0..3}, stride 16) -> 16 row-loads in flight per
// wave. Invalid streams clamp their index to stream 0's row and are masked
// out of the accumulate. Stream positions within a group are consecutive, so
// s0 invalid => s1..s3 invalid (loop exit is safe).
__global__ __launch_bounds__(256) void aggregate(
    const unsigned short* __restrict__ h, const int* __restrict__ row_start,
    const int* __restrict__ csr_src, unsigned short* __restrict__ out) {
  int node = blockIdx.x*4 + (threadIdx.x >> 6);
  if (node >= NN) return;
  int lane = threadIdx.x & 63;
  int grp = lane >> 4, l15 = lane & 15;
  int p0 = row_start[node], p1 = row_start[node+1];

  float acc[8];
  #pragma unroll
  for (int j = 0; j < 8; ++j) acc[j] = 0.f;

  int p = p0 + grp*4;
  int s0 = (p   < p1) ? csr_src[p]   : -1;
  int s1 = (p+1 < p1) ? csr_src[p+1] : -1;
  int s2 = (p+2 < p1) ? csr_src[p+2] : -1;
  int s3 = (p+3 < p1) ? csr_src[p+3] : -1;

  while (s0 >= 0) {
    int pn = p + 16;
    int t0 = (pn   < p1) ? csr_src[pn]   : -1;
    int t1 = (pn+1 < p1) ? csr_src[pn+1] : -1;
    int t2 = (pn+2 < p1) ? csr_src[pn+2] : -1;
    int t3 = (pn+3 < p1) ? csr_src[pn+3] : -1;

    float m1 = (s1 >= 0) ? 1.f : 0.f;
    float m2 = (s2 >= 0) ? 1.f : 0.f;
    float m3 = (s3 >= 0) ? 1.f : 0.f;
    int c1 = (s1 >= 0) ? s1 : s0;
    int c2 = (s2 >= 0) ? s2 : s0;
    int c3 = (s3 >= 0) ? s3 : s0;

    uint4 v0 = *(const uint4*)(h + (size_t)s0*128 + l15*8);
    uint4 v1 = *(const uint4*)(h + (size_t)c1*128 + l15*8);
    uint4 v2 = *(const uint4*)(h + (size_t)c2*128 + l15*8);
    uint4 v3 = *(const uint4*)(h + (size_t)c3*128 + l15*8);

    acc[0] += __uint_as_float(v0.x << 16);
    acc[1] += __uint_as_float(v0.x & 0xffff0000u);
    acc[2] += __uint_as_float(v0.y << 16);
    acc[3] += __uint_as_float(v0.y & 0xffff0000u);
    acc[4] += __uint_as_float(v0.z << 16);
    acc[5] += __uint_as_float(v0.z & 0xffff0000u);
    acc[6] += __uint_as_float(v0.w << 16);
    acc[7] += __uint_as_float(v0.w & 0xffff0000u);

    acc[0] = fmaf(m1, __uint_as_float(v1.x << 16), acc[0]);
    acc[1] = fmaf(m1, __uint_as_float(v1.x & 0xffff0000u), acc[1]);
    acc[2] = fmaf(m1, __uint_as_float(v1.y << 16), acc[2]);
    acc[3] = fmaf(m1, __uint_as_float(v1.y & 0xffff0000u), acc[3]);
    acc[4] = fmaf(m1, __uint_as_float(v1.z << 16), acc[4]);
    acc[5] = fmaf(m1, __uint_as_float(v1.z & 0xffff0000u), acc[5]);
    acc[6] = fmaf(m1, __uint_as_float(v1.w << 16), acc[6]);
    acc[7] = fmaf(m1, __uint_as_float(v1.w & 0xffff0000u), acc[7]);

    acc[0] = fmaf(m2, __uint_as_float(v2.x << 16), acc[0]);
    acc[1] = fmaf(m2, __uint_as_float(v2.x & 0xffff0000u), acc[1]);
    acc[2] = fmaf(m2, __uint_as_float(v2.y << 16), acc[2]);
    acc[3] = fmaf(m2, __uint_as_float(v2.y & 0xffff0000u), acc[3]);
    acc[4] = fmaf(m2, __uint_as_float(v2.z << 16), acc[4]);
    acc[5] = fmaf(m2, __uint_as_float(v2.z & 0xffff0000u), acc[5]);
    acc[6] = fmaf(m2, __uint_as_float(v2.w << 16), acc[6]);
    acc[7] = fmaf(m2, __uint_as_float(v2.w & 0xffff0000u), acc[7]);

    acc[0] = fmaf(m3, __uint_as_float(v3.x << 16), acc[0]);
    acc[1] = fmaf(m3, __uint_as_float(v3.x & 0xffff0000u), acc[1]);
    acc[2] = fmaf(m3, __uint_as_float(v3.y << 16), acc[2]);
    acc[3] = fmaf(m3, __uint_as_float(v3.y & 0xffff0000u), acc[3]);
    acc[4] = fmaf(m3, __uint_as_float(v3.z << 16), acc[4]);
    acc[5] = fmaf(m3, __uint_as_float(v3.z & 0xffff0000u), acc[5]);
    acc[6] = fmaf(m3, __uint_as_float(v3.w << 16), acc[6]);
    acc[7] = fmaf(m3, __uint_as_float(v3.w & 0xffff0000u), acc[7]);

    p = pn; s0 = t0; s1 = t1; s2 = t2; s3 = t3;
  }

  #pragma unroll
  for (int j = 0; j < 8; ++j) {
    acc[j] += __shfl_xor(acc[j], 16);
    acc[j] += __shfl_xor(acc[j], 32);
  }

  int d = p1 - p0;
  float inv = 1.0f / (float)(d > 1 ? d : 1);
  if (lane < 16) {
    uint4 o;
    o.x = ((unsigned)f2b(acc[1]*inv) << 16) | f2b(acc[0]*inv);
    o.y = ((unsigned)f2b(acc[3]*inv) << 16) | f2b(acc[2]*inv);
    o.z = ((unsigned)f2b(acc[5]*inv) << 16) | f2b(acc[4]*inv);
    o.w = ((unsigned)f2b(acc[7]*inv) << 16) | f2b(acc[6]*inv);
    *(uint4*)(out + (size_t)node*128 + l15*8) = o;
  }
}

// fused SAGE layer: hout = ELU( [agg|root](bf16) @ W^T(bf16) + bias )
// Weights staged ONCE per block into LDS in fragment-major layout.
__global__ __launch_bounds__(256, 2) void sage_mfma(
    const unsigned short* __restrict__ aggb, const unsigned short* __restrict__ rootb,
    const unsigned short* __restrict__ Wfrag, const float* __restrict__ bias,
    unsigned short* __restrict__ hout) {
  __shared__ unsigned short w[32768];   // 64KB
  int t = threadIdx.x;
  {
    const uint4* src = (const uint4*)Wfrag;
    uint4* dst = (uint4*)w;
    #pragma unroll
    for (int it = 0; it < 16; ++it) dst[it*256 + t] = src[it*256 + t];
  }
  __syncthreads();

  int lane = t & 63, wv = t >> 6;
  int l15 = lane & 15, lg = lane >> 4;
  int m0 = blockIdx.x*128 + wv*32;
  int row0 = m0 + l15;      if (row0 > NN-1) row0 = NN-1;
  int row1 = m0 + 16 + l15; if (row1 > NN-1) row1 = NN-1;

  f32x4 acc[2][8];
  #pragma unroll
  for (int mt = 0; mt < 2; ++mt)
    #pragma unroll
    for (int jf = 0; jf < 8; ++jf) acc[mt][jf] = (f32x4){0.f,0.f,0.f,0.f};

  #pragma unroll
  for (int kc = 0; kc < 8; ++kc) {
    const unsigned short* ab = (kc < 4) ? aggb : rootb;
    int kof = (kc & 3)*32 + 8*lg;
    bf16x8 a0 = *(const bf16x8*)(ab + (size_t)row0*128 + kof);
    bf16x8 a1 = *(const bf16x8*)(ab + (size_t)row1*128 + kof);
    #pragma unroll
    for (int jf = 0; jf < 8; ++jf) {
      bf16x8 b = *(const bf16x8*)(w + (kc*8 + jf)*512 + lane*8);
      acc[0][jf] = __builtin_amdgcn_mfma_f32_16x16x32_bf16(a0, b, acc[0][jf], 0, 0, 0);
      acc[1][jf] = __builtin_amdgcn_mfma_f32_16x16x32_bf16(a1, b, acc[1][jf], 0, 0, 0);
    }
  }

  #pragma unroll
  for (int mt = 0; mt < 2; ++mt) {
    #pragma unroll
    for (int jf = 0; jf < 8; ++jf) {
      int col = jf*16 + l15;
      float bj = bias[col];
      #pragma unroll
      for (int r = 0; r < 4; ++r) {
        int node = m0 + mt*16 + 4*lg + r;
        float v = acc[mt][jf][r] + bj;
        v = (v > 0.f) ? v : (expf(v) - 1.0f);    // ELU
        if (node < NN) hout[(size_t)node*128 + col] = f2b(v);
      }
    }
  }
}

__global__ void max_pool_partial(const unsigned short* __restrict__ h,
                                 const int* __restrict__ gstart,
                                 float* __restrict__ part) {
  int g = blockIdx.x, s = blockIdx.y, c = threadIdx.x;
  int n0 = gstart[g], n1 = gstart[g+1];
  int cnt = n1 - n0;
  int per = (cnt + MP_SLICES - 1) / MP_SLICES;
  int a = n0 + s*per;
  int b = a + per; if (b > n1) b = n1;
  float m = -INFINITY;
  for (int n = a; n < b; ++n) m = fmaxf(m, b2f(h[(size_t)n*DIM + c]));
  part[((size_t)g*MP_SLICES + s)*DIM + c] = m;
}

// classify also folds the maxpool slice-reduction
__global__ void classify(const float* __restrict__ part,
                         const float* __restrict__ Wc1, const float* __restrict__ bc1,
                         const float* __restrict__ Wc2, const float* __restrict__ bc2,
                         float* __restrict__ out) {
  int g = blockIdx.x, t = threadIdx.x;   // 128 threads
  __shared__ float row[128];
  __shared__ float rv[64];
  float m = -INFINITY;
  #pragma unroll
  for (int s = 0; s < MP_SLICES; ++s)
    m = fmaxf(m, part[((size_t)g*MP_SLICES + s)*DIM + t]);
  row[t] = m;
  __syncthreads();
  if (t < 64) {
    float acc = bc1[t];
    for (int k = 0; k < 128; ++k) acc += row[k] * Wc1[t*128 + k];
    rv[t] = acc;
    out[1280 + g*64 + t] = acc;          // rv output (second tuple element)
  }
  __syncthreads();
  if (t < 10) {
    float o = bc2[t];
    for (int k = 0; k < 64; ++k) o += rv[k] * Wc2[t*64 + k];
    out[g*10 + t] = o;                   // logits (first tuple element)
  }
}

extern "C" void kernel_launch(void* const* d_in, const int* in_sizes, int n_in,
                              void* d_out, int out_size, void* d_ws, size_t ws_size,
                              hipStream_t stream) {
  const float* x     = (const float*)d_in[0];
  const void*  edge  = d_in[1];
  const void*  batch = d_in[2];
  const float* gamma = (const float*)d_in[3];
  const float* beta  = (const float*)d_in[4];
  const float* W1l   = (const float*)d_in[5];
  const float* b1    = (const float*)d_in[6];
  const float* W1r   = (const float*)d_in[7];
  const float* W2l   = (const float*)d_in[8];
  const float* b2    = (const float*)d_in[9];
  const float* W2r   = (const float*)d_in[10];
  const float* Wc1   = (const float*)d_in[11];
  const float* bc1   = (const float*)d_in[12];
  const float* Wc2   = (const float*)d_in[13];
  const float* bc2   = (const float*)d_in[14];
  char* ws = (char*)d_ws;
  float* out = (float*)d_out;
  if (ws_size < (size_t)WS_NEED) return;

  int*   flag   = (int*)  (ws + OFF_FLAG);
  float* sc     = (float*)(ws + OFF_SCALE);
  float* sh     = (float*)(ws + OFF_SHIFT);
  int*   gstart = (int*)  (ws + OFF_GSTART);
  int*   tot    = (int*)  (ws + OFF_TOT);
  float* psum   = (float*)(ws + OFF_PSUM);
  float* psq    = (float*)(ws + OFF_PSQ);
  unsigned short* Wfrag1 = (unsigned short*)(ws + OFF_WC1);
  unsigned short* Wfrag2 = (unsigned short*)(ws + OFF_WC2);
  int*   rstart = (int*)  (ws + OFF_RSTART);
  int*   csr    = (int*)  (ws + OFF_CSR);
  float* part   = (float*)(ws + OFF_PART);
  int*   hist   = (int*)  (ws + OFF_HIST);
  int*   offg   = (int*)  (ws + OFF_OFFG);
  unsigned* bpack = (unsigned*)(ws + OFF_BEDGE);
  unsigned short* h0b  = (unsigned short*)(ws + OFF_H0B);
  unsigned short* h1b  = (unsigned short*)(ws + OFF_H1B);
  unsigned short* aggb = (unsigned short*)(ws + OFF_AGGB);
  unsigned short* h2b  = h0b;   // reuse

  k1_prep<<<K1_TOTAL, 256, 0, stream>>>(W1l, W1r, W2l, W2r, Wfrag1, Wfrag2,
                                        edge, flag, hist, x, psum, psq);
  k2_scan<<<K2_TOTAL, 512, 0, stream>>>(hist, offg, tot, psum, psq,
                                        gamma, beta, sc, sh, batch, flag, gstart);
  part_scatter<<<PNBLK, 256, 0, stream>>>(edge, flag, offg, tot, bpack);
  k4_csr_bn<<<K4_TOTAL, 256, 0, stream>>>(bpack, tot, rstart, csr, x, sc, sh, h0b);

  aggregate<<<(NN+3)/4, 256, 0, stream>>>(h0b, rstart, csr, aggb);
  sage_mfma<<<(NN+127)/128, 256, 0, stream>>>(aggb, h0b, Wfrag1, b1, h1b);
  aggregate<<<(NN+3)/4, 256, 0, stream>>>(h1b, rstart, csr, aggb);
  sage_mfma<<<(NN+127)/128, 256, 0, stream>>>(aggb, h1b, Wfrag2, b2, h2b);

  {
    dim3 grid(NGR, MP_SLICES);
    max_pool_partial<<<grid, 128, 0, stream>>>(h2b, gstart, part);
  }
  classify<<<NGR, 128, 0, stream>>>(part, Wc1, bc1, Wc2, bc2, out);
}

// Round 13
// 154.676 us; speedup vs baseline: 1.3911x; 1.3911x over previous
//
#include <hip/hip_runtime.h>
#include <math.h>

#define NN 50000
#define NE 800000
#define DIM 128
#define NGR 128
#define MP_SLICES 16

// edge partition params
#define PCHUNK 2048
#define PNBLK 391      // ceil(NE/PCHUNK)
#define NBIN 196       // bin = dst>>8 ; 256 nodes per bin

// bn stats blocks
#define BN_NB 1024
#define BN_R1 16       // stage-1 reduction blocks (each covers 64 partials)

// K1 fat-kernel block ranges: [0,32)=pack, [32,423)=hist, [423,1447)=bn_stats
#define K1_PACK_NB   32
#define K1_HIST_END  (K1_PACK_NB + PNBLK)          // 423
#define K1_TOTAL     (K1_HIST_END + BN_NB)         // 1447
// K2: [0,196)=scan_cols, [196,212)=bn_reduce1, [212,310)=graph_bounds (512 thr)
#define K2_GB_NB     98
#define K2_TOTAL     (NBIN + BN_R1 + K2_GB_NB)     // 310
// K4: [0,196)=csr_build, [196,196+6250)=bn_apply
#define K4_BNA_NB    6250
#define K4_TOTAL     (NBIN + K4_BNA_NB)            // 6446

typedef short bf16x8 __attribute__((ext_vector_type(8)));
typedef float f32x4  __attribute__((ext_vector_type(4)));

// ---- workspace layout (bytes) ----
#define OFF_FLAG    0
#define OFF_SCALE   1024
#define OFF_SHIFT   2048
#define OFF_GSTART  4096                   // 129 ints
#define OFF_TOT     16384                  // NBIN ints
#define OFF_WC1     32768                  // frag-major weights, 64KB
#define OFF_WC2     98304                  // 64KB, ends 163840
#define OFF_PSUM2   163840                 // BN_R1*128*4 = 8KB
#define OFF_PSQ2    172032                 // 8KB, ends 180224
#define OFF_PSUM    262144                 // BN_NB*128*4 = 512KB, ends 786432
#define OFF_PSQ     786432                 // 512KB, ends 1310720
#define OFF_RSTART  1310720                // (NN+1) ints, ends 1510724
#define OFF_CSR     1572864                // 3.2MB, ends 4772864
#define OFF_PART    4772864                // 1MB maxpool partials, ends 5821440
#define OFF_HIST    5821440                // PNBLK*NBIN ints = 306544, ends 6127984
#define OFF_OFFG    6127984                // 306544, ends 6434528
#define OFF_BEDGE   6553600                // 3.2MB packed u32 (dst8|src16), ends 9753600
#define OFF_H0B     13000000               // 12.8MB bf16
#define OFF_H1B     26000000               // 12.8MB bf16
#define OFF_AGGB    39000000               // 12.8MB bf16
#define WS_NEED     52000000

__device__ __forceinline__ unsigned short f2b(float f) {
  union { float f; unsigned u; } v; v.f = f;
  unsigned r = (v.u + 0x7FFF + ((v.u >> 16) & 1)) >> 16;   // RNE
  return (unsigned short)r;
}
__device__ __forceinline__ float b2f(unsigned short h) {
  union { unsigned u; float f; } v; v.u = ((unsigned)h) << 16;
  return v.f;
}

// ---- K1: pack_weights || part_hist || bn_stats (all independent) ----
__global__ __launch_bounds__(256) void k1_prep(
    const float* __restrict__ W1l, const float* __restrict__ W1r,
    const float* __restrict__ W2l, const float* __restrict__ W2r,
    unsigned short* __restrict__ Wf1, unsigned short* __restrict__ Wf2,
    const void* __restrict__ edge, int* __restrict__ flag,
    int* __restrict__ hist,
    const float* __restrict__ x, float* __restrict__ psum, float* __restrict__ psq) {
  int b = blockIdx.x, t = threadIdx.x;

  if (b < K1_PACK_NB) {
    int gi = b*256 + t;
    if (gi == 0) {
      const unsigned* eu = (const unsigned*)edge;
      unsigned acc = 0;
      for (int i = 0; i < 64; ++i) acc |= eu[2*i+1];
      *flag = (acc == 0) ? 1 : 0;
    }
    int layer = gi >> 12;        // 0 or 1
    int i = gi & 4095;           // frag*64 + lane, i < 4096
    const float* Wl = layer ? W2l : W1l;
    const float* Wr = layer ? W2r : W1r;
    unsigned short* Wfrag = layer ? Wf2 : Wf1;
    int lane = i & 63, f = i >> 6;
    int kc = f >> 3, jf = f & 7;
    int j  = jf*16 + (lane & 15);
    int k0 = kc*32 + 8*(lane >> 4);
    #pragma unroll
    for (int e = 0; e < 8; ++e) {
      int k = k0 + e;
      float v = (k < 128) ? Wl[j*128 + k] : Wr[j*128 + (k-128)];
      Wfrag[(size_t)i*8 + e] = f2b(v);
    }
    return;
  }

  if (b < K1_HIST_END) {
    __shared__ int lh[NBIN];
    __shared__ int wflag;
    int bb = b - K1_PACK_NB;
    if (t < NBIN) lh[t] = 0;
    if (t == 0) {   // self-probe width (512B, L2-hot)
      const unsigned* eu = (const unsigned*)edge;
      unsigned acc = 0;
      for (int i = 0; i < 64; ++i) acc |= eu[2*i+1];
      wflag = (acc == 0) ? 1 : 0;
    }
    __syncthreads();
    bool w = (wflag != 0);
    int e0 = bb*PCHUNK, e1 = e0 + PCHUNK; if (e1 > NE) e1 = NE;
    for (int e = e0 + t; e < e1; e += 256) {
      int d = w ? (int)((const long long*)edge)[NE + e] : ((const int*)edge)[NE + e];
      atomicAdd(&lh[d >> 8], 1);
    }
    __syncthreads();
    if (t < NBIN) hist[bb*NBIN + t] = lh[t];
    return;
  }

  {
    // bn_stats block
    __shared__ float ss[128], sq[128];
    int bb = b - K1_HIST_END;
    int col  = t & 127;
    int half = t >> 7;
    float s = 0.f, q = 0.f;
    for (int r = bb*2 + half; r < NN; r += 2*BN_NB) {
      float v = x[(size_t)r*DIM + col];
      s += v; q += v*v;
    }
    if (half) { ss[col] = s; sq[col] = q; }
    __syncthreads();
    if (!half) {
      psum[bb*DIM + col] = s + ss[col];
      psq [bb*DIM + col] = q + sq[col];
    }
    return;
  }
}

// ---- K2: part_scan_cols || bn_reduce1 (1024->16) || graph_bounds ----
__global__ __launch_bounds__(512) void k2_scan(
    const int* __restrict__ hist, int* __restrict__ offg, int* __restrict__ tot,
    const float* __restrict__ psum, const float* __restrict__ psq,
    float* __restrict__ psum2, float* __restrict__ psq2,
    const void* __restrict__ batch, const int* __restrict__ flag,
    int* __restrict__ gstart) {
  int b = blockIdx.x, t = threadIdx.x;

  if (b < NBIN) {
    __shared__ int sm[512];
    int bin = b;
    int v = (t < PNBLK) ? hist[t*NBIN + bin] : 0;
    sm[t] = v;
    __syncthreads();
    for (int off = 1; off < 512; off <<= 1) {
      int xx = (t >= off) ? sm[t-off] : 0;
      __syncthreads();
      sm[t] += xx;
      __syncthreads();
    }
    if (t < PNBLK) offg[t*NBIN + bin] = sm[t] - v;
    if (t == 511) tot[bin] = sm[511];
    return;
  }

  if (b < NBIN + BN_R1) {
    // bn_reduce1: block r reduces partial rows [r*64, r*64+64) for all cols.
    // 4 sub-groups of 128 threads, 16 coalesced iterations each.
    __shared__ float ss[4][128], qq[4][128];
    int r = b - NBIN;
    int col = t & 127, sub = t >> 7;          // sub in [0,4)
    int base = r*64 + sub*16;
    float s = 0.f, q = 0.f;
    #pragma unroll
    for (int i = 0; i < 16; ++i) {
      s += psum[(size_t)(base + i)*DIM + col];
      q += psq [(size_t)(base + i)*DIM + col];
    }
    ss[sub][col] = s; qq[sub][col] = q;
    __syncthreads();
    if (sub == 0) {
      #pragma unroll
      for (int k = 1; k < 4; ++k) { s += ss[k][col]; q += qq[k][col]; }
      psum2[r*DIM + col] = s;
      psq2 [r*DIM + col] = q;
    }
    return;
  }

  {
    // graph_bounds: gstart[g] = lower_bound(batch, g)
    int n = (b - NBIN - BN_R1)*512 + t;
    if (n > NN) return;
    bool w = (*flag != 0);
    int bn = NGR, bp = -1;
    if (n < NN) bn = w ? (int)((const long long*)batch)[n]   : ((const int*)batch)[n];
    if (n > 0)  bp = w ? (int)((const long long*)batch)[n-1] : ((const int*)batch)[n-1];
    for (int g = bp + 1; g <= bn; ++g) gstart[g] = n;
    return;
  }
}

// ---- K3: partition pass; extra block PNBLK finishes BN (16->1, sc/sh) ----
__global__ __launch_bounds__(256) void part_scatter(const void* __restrict__ edge,
                                                    const int* __restrict__ flag,
                                                    const int* __restrict__ offg,
                                                    const int* __restrict__ tot,
                                                    unsigned* __restrict__ bpack,
                                                    const float* __restrict__ psum2,
                                                    const float* __restrict__ psq2,
                                                    const float* __restrict__ gamma,
                                                    const float* __restrict__ beta,
                                                    float* __restrict__ sc,
                                                    float* __restrict__ sh) {
  int b = blockIdx.x, t = threadIdx.x;

  if (b == PNBLK) {
    // bn_final2: tiny, hidden under the 391 scatter blocks
    if (t < 128) {
      float s = 0.f, q = 0.f;
      #pragma unroll
      for (int r = 0; r < BN_R1; ++r) {
        s += psum2[r*DIM + t];
        q += psq2 [r*DIM + t];
      }
      float mu  = s * (1.0f/NN);
      float var = q * (1.0f/NN) - mu*mu;     // biased variance
      float a = gamma[t] * rsqrtf(var + 1e-5f);
      sc[t] = a;
      sh[t] = beta[t] - mu*a;
    }
    return;
  }

  __shared__ int sm[256];
  __shared__ int cur[NBIN];
  int v = (t < NBIN) ? tot[t] : 0;
  sm[t] = v;
  __syncthreads();
  for (int off = 1; off < 256; off <<= 1) {
    int xx = (t >= off) ? sm[t-off] : 0;
    __syncthreads();
    sm[t] += xx;
    __syncthreads();
  }
  if (t < NBIN) cur[t] = offg[b*NBIN + t] + sm[t] - v;   // + bstart[t]
  __syncthreads();
  bool w = (*flag != 0);
  int e0 = b*PCHUNK, e1 = e0 + PCHUNK; if (e1 > NE) e1 = NE;
  for (int e = e0 + t; e < e1; e += 256) {
    int s, d;
    if (w) {
      s = (int)((const long long*)edge)[e];
      d = (int)((const long long*)edge)[NE + e];
    } else {
      s = ((const int*)edge)[e];
      d = ((const int*)edge)[NE + e];
    }
    int pos = atomicAdd(&cur[d >> 8], 1);   // LDS atomic only
    bpack[pos] = ((unsigned)(d & 255) << 16) | (unsigned)s;   // src < 2^16
  }
}

// ---- K4: csr_build || bn_apply ----
__global__ __launch_bounds__(256) void k4_csr_bn(
    const unsigned* __restrict__ bpack, const int* __restrict__ tot,
    int* __restrict__ row_start, int* __restrict__ csr_src,
    const float* __restrict__ x, const float* __restrict__ sc,
    const float* __restrict__ sh, unsigned short* __restrict__ h0) {
  int b = blockIdx.x, t = threadIdx.x;

  if (b < NBIN) {
    __shared__ int sm[256];
    __shared__ int ldeg[256];
    __shared__ int lscan[256];
    __shared__ int lcur[256];
    __shared__ int e0s, e1s;
    int i = b;
    int v = (t < NBIN) ? tot[t] : 0;
    sm[t] = v;
    __syncthreads();
    for (int off = 1; off < 256; off <<= 1) {
      int xx = (t >= off) ? sm[t-off] : 0;
      __syncthreads();
      sm[t] += xx;
      __syncthreads();
    }
    if (t == i) { e0s = sm[t] - v; e1s = sm[t]; }
    ldeg[t] = 0;
    __syncthreads();
    int e0 = e0s, e1 = e1s;
    for (int p = e0 + t; p < e1; p += 256) {
      unsigned pv = bpack[p];
      atomicAdd(&ldeg[(pv >> 16) & 255], 1);
    }
    __syncthreads();
    if (t == 0) {
      int run = 0;
      for (int k = 0; k < 256; ++k) { lscan[k] = run; run += ldeg[k]; }
    }
    __syncthreads();
    int node = i*256 + t;
    if (node <= NN) row_start[node] = e0 + lscan[t];
    lcur[t] = lscan[t];
    __syncthreads();
    for (int p = e0 + t; p < e1; p += 256) {
      unsigned pv = bpack[p];
      int d8 = (pv >> 16) & 255;
      int s  = (int)(pv & 0xffffu);
      int pos = atomicAdd(&lcur[d8], 1);
      csr_src[e0 + pos] = s;
    }
    return;
  }

  {
    // bn_apply: x fp32 -> h0 bf16
    long i = (long)(b - NBIN)*256 + t;
    if (i >= (long)NN*DIM/4) return;
    int c4 = (int)((i*4) & (DIM-1));
    float4 v = ((const float4*)x)[i];
    ushort4 r;
    r.x = f2b(v.x*sc[c4+0] + sh[c4+0]);
    r.y = f2b(v.y*sc[c4+1] + sh[c4+1]);
    r.z = f2b(v.z*sc[c4+2] + sh[c4+2]);
    r.w = f2b(v.w*sc[c4+3] + sh[c4+3]);
    ((ushort4*)h0)[i] = r;
    return;
  }
}

// one wave per node; 4 lane-groups of 16, each group runs FOUR independent
// neighbor streams -> 16 row-loads in flight per wave.
__global__ __launch_bounds__(256) void aggregate(
    const unsigned short* __restrict__ h, const int* __restrict__ row_start,
    const int* __restrict__ csr_src, unsigned short* __restrict__ out) {
  int node = blockIdx.x*4 + (threadIdx.x >> 6);
  if (node >= NN) return;
  int lane = threadIdx.x & 63;
  int grp = lane >> 4, l15 = lane & 15;
  int p0 = row_start[node], p1 = row_start[node+1];

  float acc[8];
  #pragma unroll
  for (int j = 0; j < 8; ++j) acc[j] = 0.f;

  int p = p0 + grp*4;
  int s0 = (p   < p1) ? csr_src[p]   : -1;
  int s1 = (p+1 < p1) ? csr_src[p+1] : -1;
  int s2 = (p+2 < p1) ? csr_src[p+2] : -1;
  int s3 = (p+3 < p1) ? csr_src[p+3] : -1;

  while (s0 >= 0) {
    int pn = p + 16;
    int t0 = (pn   < p1) ? csr_src[pn]   : -1;
    int t1 = (pn+1 < p1) ? csr_src[pn+1] : -1;
    int t2 = (pn+2 < p1) ? csr_src[pn+2] : -1;
    int t3 = (pn+3 < p1) ? csr_src[pn+3] : -1;

    float m1 = (s1 >= 0) ? 1.f : 0.f;
    float m2 = (s2 >= 0) ? 1.f : 0.f;
    float m3 = (s3 >= 0) ? 1.f : 0.f;
    int c1 = (s1 >= 0) ? s1 : s0;
    int c2 = (s2 >= 0) ? s2 : s0;
    int c3 = (s3 >= 0) ? s3 : s0;

    uint4 v0 = *(const uint4*)(h + (size_t)s0*128 + l15*8);
    uint4 v1 = *(const uint4*)(h + (size_t)c1*128 + l15*8);
    uint4 v2 = *(const uint4*)(h + (size_t)c2*128 + l15*8);
    uint4 v3 = *(const uint4*)(h + (size_t)c3*128 + l15*8);

    acc[0] += __uint_as_float(v0.x << 16);
    acc[1] += __uint_as_float(v0.x & 0xffff0000u);
    acc[2] += __uint_as_float(v0.y << 16);
    acc[3] += __uint_as_float(v0.y & 0xffff0000u);
    acc[4] += __uint_as_float(v0.z << 16);
    acc[5] += __uint_as_float(v0.z & 0xffff0000u);
    acc[6] += __uint_as_float(v0.w << 16);
    acc[7] += __uint_as_float(v0.w & 0xffff0000u);

    acc[0] = fmaf(m1, __uint_as_float(v1.x << 16), acc[0]);
    acc[1] = fmaf(m1, __uint_as_float(v1.x & 0xffff0000u), acc[1]);
    acc[2] = fmaf(m1, __uint_as_float(v1.y << 16), acc[2]);
    acc[3] = fmaf(m1, __uint_as_float(v1.y & 0xffff0000u), acc[3]);
    acc[4] = fmaf(m1, __uint_as_float(v1.z << 16), acc[4]);
    acc[5] = fmaf(m1, __uint_as_float(v1.z & 0xffff0000u), acc[5]);
    acc[6] = fmaf(m1, __uint_as_float(v1.w << 16), acc[6]);
    acc[7] = fmaf(m1, __uint_as_float(v1.w & 0xffff0000u), acc[7]);

    acc[0] = fmaf(m2, __uint_as_float(v2.x << 16), acc[0]);
    acc[1] = fmaf(m2, __uint_as_float(v2.x & 0xffff0000u), acc[1]);
    acc[2] = fmaf(m2, __uint_as_float(v2.y << 16), acc[2]);
    acc[3] = fmaf(m2, __uint_as_float(v2.y & 0xffff0000u), acc[3]);
    acc[4] = fmaf(m2, __uint_as_float(v2.z << 16), acc[4]);
    acc[5] = fmaf(m2, __uint_as_float(v2.z & 0xffff0000u), acc[5]);
    acc[6] = fmaf(m2, __uint_as_float(v2.w << 16), acc[6]);
    acc[7] = fmaf(m2, __uint_as_float(v2.w & 0xffff0000u), acc[7]);

    acc[0] = fmaf(m3, __uint_as_float(v3.x << 16), acc[0]);
    acc[1] = fmaf(m3, __uint_as_float(v3.x & 0xffff0000u), acc[1]);
    acc[2] = fmaf(m3, __uint_as_float(v3.y << 16), acc[2]);
    acc[3] = fmaf(m3, __uint_as_float(v3.y & 0xffff0000u), acc[3]);
    acc[4] = fmaf(m3, __uint_as_float(v3.z << 16), acc[4]);
    acc[5] = fmaf(m3, __uint_as_float(v3.z & 0xffff0000u), acc[5]);
    acc[6] = fmaf(m3, __uint_as_float(v3.w << 16), acc[6]);
    acc[7] = fmaf(m3, __uint_as_float(v3.w & 0xffff0000u), acc[7]);

    p = pn; s0 = t0; s1 = t1; s2 = t2; s3 = t3;
  }

  #pragma unroll
  for (int j = 0; j < 8; ++j) {
    acc[j] += __shfl_xor(acc[j], 16);
    acc[j] += __shfl_xor(acc[j], 32);
  }

  int d = p1 - p0;
  float inv = 1.0f / (float)(d > 1 ? d : 1);
  if (lane < 16) {
    uint4 o;
    o.x = ((unsigned)f2b(acc[1]*inv) << 16) | f2b(acc[0]*inv);
    o.y = ((unsigned)f2b(acc[3]*inv) << 16) | f2b(acc[2]*inv);
    o.z = ((unsigned)f2b(acc[5]*inv) << 16) | f2b(acc[4]*inv);
    o.w = ((unsigned)f2b(acc[7]*inv) << 16) | f2b(acc[6]*inv);
    *(uint4*)(out + (size_t)node*128 + l15*8) = o;
  }
}

// fused SAGE layer: hout = ELU( [agg|root](bf16) @ W^T(bf16) + bias )
__global__ __launch_bounds__(256, 2) void sage_mfma(
    const unsigned short* __restrict__ aggb, const unsigned short* __restrict__ rootb,
    const unsigned short* __restrict__ Wfrag, const float* __restrict__ bias,
    unsigned short* __restrict__ hout) {
  __shared__ unsigned short w[32768];   // 64KB
  int t = threadIdx.x;
  {
    const uint4* src = (const uint4*)Wfrag;
    uint4* dst = (uint4*)w;
    #pragma unroll
    for (int it = 0; it < 16; ++it) dst[it*256 + t] = src[it*256 + t];
  }
  __syncthreads();

  int lane = t & 63, wv = t >> 6;
  int l15 = lane & 15, lg = lane >> 4;
  int m0 = blockIdx.x*128 + wv*32;
  int row0 = m0 + l15;      if (row0 > NN-1) row0 = NN-1;
  int row1 = m0 + 16 + l15; if (row1 > NN-1) row1 = NN-1;

  f32x4 acc[2][8];
  #pragma unroll
  for (int mt = 0; mt < 2; ++mt)
    #pragma unroll
    for (int jf = 0; jf < 8; ++jf) acc[mt][jf] = (f32x4){0.f,0.f,0.f,0.f};

  #pragma unroll
  for (int kc = 0; kc < 8; ++kc) {
    const unsigned short* ab = (kc < 4) ? aggb : rootb;
    int kof = (kc & 3)*32 + 8*lg;
    bf16x8 a0 = *(const bf16x8*)(ab + (size_t)row0*128 + kof);
    bf16x8 a1 = *(const bf16x8*)(ab + (size_t)row1*128 + kof);
    #pragma unroll
    for (int jf = 0; jf < 8; ++jf) {
      bf16x8 b = *(const bf16x8*)(w + (kc*8 + jf)*512 + lane*8);
      acc[0][jf] = __builtin_amdgcn_mfma_f32_16x16x32_bf16(a0, b, acc[0][jf], 0, 0, 0);
      acc[1][jf] = __builtin_amdgcn_mfma_f32_16x16x32_bf16(a1, b, acc[1][jf], 0, 0, 0);
    }
  }

  #pragma unroll
  for (int mt = 0; mt < 2; ++mt) {
    #pragma unroll
    for (int jf = 0; jf < 8; ++jf) {
      int col = jf*16 + l15;
      float bj = bias[col];
      #pragma unroll
      for (int r = 0; r < 4; ++r) {
        int node = m0 + mt*16 + 4*lg + r;
        float v = acc[mt][jf][r] + bj;
        v = (v > 0.f) ? v : (expf(v) - 1.0f);    // ELU
        if (node < NN) hout[(size_t)node*128 + col] = f2b(v);
      }
    }
  }
}

__global__ void max_pool_partial(const unsigned short* __restrict__ h,
                                 const int* __restrict__ gstart,
                                 float* __restrict__ part) {
  int g = blockIdx.x, s = blockIdx.y, c = threadIdx.x;
  int n0 = gstart[g], n1 = gstart[g+1];
  int cnt = n1 - n0;
  int per = (cnt + MP_SLICES - 1) / MP_SLICES;
  int a = n0 + s*per;
  int b = a + per; if (b > n1) b = n1;
  float m = -INFINITY;
  for (int n = a; n < b; ++n) m = fmaxf(m, b2f(h[(size_t)n*DIM + c]));
  part[((size_t)g*MP_SLICES + s)*DIM + c] = m;
}

// classify also folds the maxpool slice-reduction
__global__ void classify(const float* __restrict__ part,
                         const float* __restrict__ Wc1, const float* __restrict__ bc1,
                         const float* __restrict__ Wc2, const float* __restrict__ bc2,
                         float* __restrict__ out) {
  int g = blockIdx.x, t = threadIdx.x;   // 128 threads
  __shared__ float row[128];
  __shared__ float rv[64];
  float m = -INFINITY;
  #pragma unroll
  for (int s = 0; s < MP_SLICES; ++s)
    m = fmaxf(m, part[((size_t)g*MP_SLICES + s)*DIM + t]);
  row[t] = m;
  __syncthreads();
  if (t < 64) {
    float acc = bc1[t];
    for (int k = 0; k < 128; ++k) acc += row[k] * Wc1[t*128 + k];
    rv[t] = acc;
    out[1280 + g*64 + t] = acc;          // rv output (second tuple element)
  }
  __syncthreads();
  if (t < 10) {
    float o = bc2[t];
    for (int k = 0; k < 64; ++k) o += rv[k] * Wc2[t*64 + k];
    out[g*10 + t] = o;                   // logits (first tuple element)
  }
}

extern "C" void kernel_launch(void* const* d_in, const int* in_sizes, int n_in,
                              void* d_out, int out_size, void* d_ws, size_t ws_size,
                              hipStream_t stream) {
  const float* x     = (const float*)d_in[0];
  const void*  edge  = d_in[1];
  const void*  batch = d_in[2];
  const float* gamma = (const float*)d_in[3];
  const float* beta  = (const float*)d_in[4];
  const float* W1l   = (const float*)d_in[5];
  const float* b1    = (const float*)d_in[6];
  const float* W1r   = (const float*)d_in[7];
  const float* W2l   = (const float*)d_in[8];
  const float* b2    = (const float*)d_in[9];
  const float* W2r   = (const float*)d_in[10];
  const float* Wc1   = (const float*)d_in[11];
  const float* bc1   = (const float*)d_in[12];
  const float* Wc2   = (const float*)d_in[13];
  const float* bc2   = (const float*)d_in[14];
  char* ws = (char*)d_ws;
  float* out = (float*)d_out;
  if (ws_size < (size_t)WS_NEED) return;

  int*   flag   = (int*)  (ws + OFF_FLAG);
  float* sc     = (float*)(ws + OFF_SCALE);
  float* sh     = (float*)(ws + OFF_SHIFT);
  int*   gstart = (int*)  (ws + OFF_GSTART);
  int*   tot    = (int*)  (ws + OFF_TOT);
  float* psum   = (float*)(ws + OFF_PSUM);
  float* psq    = (float*)(ws + OFF_PSQ);
  float* psum2  = (float*)(ws + OFF_PSUM2);
  float* psq2   = (float*)(ws + OFF_PSQ2);
  unsigned short* Wfrag1 = (unsigned short*)(ws + OFF_WC1);
  unsigned short* Wfrag2 = (unsigned short*)(ws + OFF_WC2);
  int*   rstart = (int*)  (ws + OFF_RSTART);
  int*   csr    = (int*)  (ws + OFF_CSR);
  float* part   = (float*)(ws + OFF_PART);
  int*   hist   = (int*)  (ws + OFF_HIST);
  int*   offg   = (int*)  (ws + OFF_OFFG);
  unsigned* bpack = (unsigned*)(ws + OFF_BEDGE);
  unsigned short* h0b  = (unsigned short*)(ws + OFF_H0B);
  unsigned short* h1b  = (unsigned short*)(ws + OFF_H1B);
  unsigned short* aggb = (unsigned short*)(ws + OFF_AGGB);
  unsigned short* h2b  = h0b;   // reuse

  k1_prep<<<K1_TOTAL, 256, 0, stream>>>(W1l, W1r, W2l, W2r, Wfrag1, Wfrag2,
                                        edge, flag, hist, x, psum, psq);
  k2_scan<<<K2_TOTAL, 512, 0, stream>>>(hist, offg, tot, psum, psq,
                                        psum2, psq2, batch, flag, gstart);
  part_scatter<<<PNBLK + 1, 256, 0, stream>>>(edge, flag, offg, tot, bpack,
                                              psum2, psq2, gamma, beta, sc, sh);
  k4_csr_bn<<<K4_TOTAL, 256, 0, stream>>>(bpack, tot, rstart, csr, x, sc, sh, h0b);

  aggregate<<<(NN+3)/4, 256, 0, stream>>>(h0b, rstart, csr, aggb);
  sage_mfma<<<(NN+127)/128, 256, 0, stream>>>(aggb, h0b, Wfrag1, b1, h1b);
  aggregate<<<(NN+3)/4, 256, 0, stream>>>(h1b, rstart, csr, aggb);
  sage_mfma<<<(NN+127)/128, 256, 0, stream>>>(aggb, h1b, Wfrag2, b2, h2b);

  {
    dim3 grid(NGR, MP_SLICES);
    max_pool_partial<<<grid, 128, 0, stream>>>(h2b, gstart, part);
  }
  classify<<<NGR, 128, 0, stream>>>(part, Wc1, bc1, Wc2, bc2, out);
}